// Round 7
// baseline (156.766 us; speedup 1.0000x reference)
//
#include <hip/hip_runtime.h>
#include <hip/hip_bf16.h>
#include <math.h>

#define B_    16
#define T1_   64
#define T2_   64
#define D_    1024
#define PROJ_ 512
#define BM    64
#define BK    32
#define NT    (D_ / BK)          // 32 K-steps per pass
#define NPASS 2                  // N split: pass p covers cols [p*256, p*256+256)
#define LDP   40                 // padded A row (shorts): 80 B stride, ~2-way banks

typedef __attribute__((ext_vector_type(8))) short bf16x8;
typedef __attribute__((ext_vector_type(4))) float f32x4;
typedef __attribute__((ext_vector_type(4))) unsigned int u32x4;

struct A8 { float4 a, b; };      // 8 fp32 of one row (32 B per thread-step)

// RNE fp32->bf16, no NaN path (inputs are finite)
__device__ __forceinline__ unsigned short f2bf(float f) {
  unsigned int u = __builtin_bit_cast(unsigned int, f);
  u += 0x7FFFu + ((u >> 16) & 1u);
  return (unsigned short)(u >> 16);
}

// tanh(a) = 1 - 2/(exp(2a)+1); v_exp_f32 + v_rcp_f32, ~5 instr, |err|~1e-6
__device__ __forceinline__ float fast_tanh(float a) {
  float t = __builtin_amdgcn_exp2f(a * 2.885390081777927f);  // exp(2a)
  return 1.0f - 2.0f * __builtin_amdgcn_rcpf(t + 1.0f);
}

// ---------------------------------------------------------------------------
// Prep: Wt fragment-ordered bf16. 16B chunk index ((t*32 + n16)*64 + lane)
// holds W[k][n], n = n16*16 + (lane&15), k = t*32 + (lane>>4)*8 + j.
// ---------------------------------------------------------------------------
__global__ __launch_bounds__(256) void make_bfrag(
    const float* __restrict__ W, unsigned short* __restrict__ wt) {
  __shared__ float tile[32][33];
  const int t  = blockIdx.x;        // k-step 0..31
  const int np = blockIdx.y;        // n-pair 0..15
  const int tx = threadIdx.x & 31;
  const int ty = threadIdx.x >> 5;  // 0..7
#pragma unroll
  for (int i = 0; i < 4; ++i)
    tile[ty + i * 8][tx] =
        W[(size_t)(t * 32 + ty + i * 8) * PROJ_ + np * 32 + tx];
  __syncthreads();
  if (threadIdx.x < 128) {
    const int sub  = threadIdx.x >> 6;   // 0..1
    const int lane = threadIdx.x & 63;
    const int llo = lane & 15, lhi = lane >> 4;
    unsigned short o[8];
#pragma unroll
    for (int j = 0; j < 8; ++j)
      o[j] = f2bf(tile[lhi * 8 + j][sub * 16 + llo]);
    const int n16 = np * 2 + sub;
    *(u32x4*)(wt + ((size_t)(t * 32 + n16) * 64 + lane) * 8) = *(const u32x4*)o;
  }
}

// ---------------------------------------------------------------------------
// Fused: one (b,t1) group of 64 rows per 256-thread block (4 waves).
// scores = v . tanh(x @ W) via bf16 MFMA -> softmax(64) -> out = attn . x
// N=512 covered in 2 full-K passes; pass p, wave w handles cols (p*4+w)*64.
// acc[4][4] reused across passes -> ~128 unified regs -> 4 blocks/CU,
// 4 independent 4-wave barrier groups, whole grid (1024 blocks) resident.
// A: depth-2 register pipeline (fp32->bf16) -> padded LDS double-buffer.
// B: register fragments from L2-resident fragment-ordered Wt.
// ---------------------------------------------------------------------------
__global__ __launch_bounds__(256, 4) void fused_kernel(
    const float* __restrict__ x, const unsigned short* __restrict__ wt,
    const float* __restrict__ v, float* __restrict__ out) {
  __shared__ unsigned short As[2][BM][LDP];   // 10.2 KB
  __shared__ float sp[BM][8];                 // per-slice score partials
  __shared__ float attn[BM];

  const int tid  = threadIdx.x;
  const int lane = tid & 63;
  const int wid  = tid >> 6;            // 0..3
  const int llo  = lane & 15, lhi = lane >> 4;
  const int bt   = blockIdx.x;
  const int m0   = bt * BM;

  // A staging map: thread -> row = tid/4, k-chunk = (tid&3)*8 (two float4)
  const int arow = tid >> 2, akc = (tid & 3) * 8;
  const float* asrc = x + (size_t)(m0 + arow) * D_ + akc;
  const u32x4* wt4 = (const u32x4*)wt;   // chunk index (t*32 + n16)*64 + lane

  for (int p = 0; p < NPASS; ++p) {
    const int slice = p * 4 + wid;       // 64-col n-slice 0..7
    const int bbase = (slice * 4) * 64 + lane;

    f32x4 acc[4][4];
#pragma unroll
    for (int mf = 0; mf < 4; ++mf)
#pragma unroll
      for (int nf = 0; nf < 4; ++nf) acc[mf][nf] = (f32x4){0.f, 0.f, 0.f, 0.f};

    __syncthreads();                     // As free from previous pass readers

    // prologue: A(0)->As[0], A(1)->s1, B(0)->rb
    A8 s0, s1;
    s0.a = *(const float4*)(asrc);
    s0.b = *(const float4*)(asrc + 4);
    s1.a = *(const float4*)(asrc + BK);
    s1.b = *(const float4*)(asrc + BK + 4);
    u32x4 rb[4];
#pragma unroll
    for (int nf = 0; nf < 4; ++nf) rb[nf] = wt4[bbase + nf * 64];
    {
      unsigned short o[8] = {f2bf(s0.a.x), f2bf(s0.a.y), f2bf(s0.a.z), f2bf(s0.a.w),
                             f2bf(s0.b.x), f2bf(s0.b.y), f2bf(s0.b.z), f2bf(s0.b.w)};
      *(u32x4*)&As[0][arow][akc] = *(const u32x4*)o;
    }
    asm volatile("s_waitcnt lgkmcnt(0)" ::: "memory");
    __builtin_amdgcn_s_barrier();

#define KSTEP(T, SLD, SCV, BR, BW)                                           \
  {                                                                          \
    bf16x8 af0 = *(const bf16x8*)&As[BR][ 0 + llo][lhi * 8];                 \
    bf16x8 af1 = *(const bf16x8*)&As[BR][16 + llo][lhi * 8];                 \
    bf16x8 af2 = *(const bf16x8*)&As[BR][32 + llo][lhi * 8];                 \
    bf16x8 af3 = *(const bf16x8*)&As[BR][48 + llo][lhi * 8];                 \
    if ((T) + 2 < NT) {                                                      \
      SLD.a = *(const float4*)(asrc + ((T) + 2) * BK);                       \
      SLD.b = *(const float4*)(asrc + ((T) + 2) * BK + 4);                   \
    }                                                                        \
    __builtin_amdgcn_s_setprio(1);                                           \
    _Pragma("unroll")                                                        \
    for (int nf = 0; nf < 4; ++nf) {                                         \
      bf16x8 bfr = *(const bf16x8*)&rb[nf];                                  \
      acc[0][nf] = __builtin_amdgcn_mfma_f32_16x16x32_bf16(af0, bfr, acc[0][nf], 0, 0, 0); \
      acc[1][nf] = __builtin_amdgcn_mfma_f32_16x16x32_bf16(af1, bfr, acc[1][nf], 0, 0, 0); \
      acc[2][nf] = __builtin_amdgcn_mfma_f32_16x16x32_bf16(af2, bfr, acc[2][nf], 0, 0, 0); \
      acc[3][nf] = __builtin_amdgcn_mfma_f32_16x16x32_bf16(af3, bfr, acc[3][nf], 0, 0, 0); \
      if ((T) + 1 < NT) rb[nf] = wt4[bbase + ((T) + 1) * 2048 + nf * 64];    \
    }                                                                        \
    __builtin_amdgcn_s_setprio(0);                                           \
    if ((T) + 1 < NT) {                                                      \
      unsigned short o[8] = {f2bf(SCV.a.x), f2bf(SCV.a.y), f2bf(SCV.a.z), f2bf(SCV.a.w), \
                             f2bf(SCV.b.x), f2bf(SCV.b.y), f2bf(SCV.b.z), f2bf(SCV.b.w)}; \
      *(u32x4*)&As[BW][arow][akc] = *(const u32x4*)o;                        \
    }                                                                        \
    asm volatile("s_waitcnt lgkmcnt(0)" ::: "memory");                       \
    __builtin_amdgcn_s_barrier();                                            \
  }

    for (int t = 0; t < NT; t += 2) {
      KSTEP(t,     s0, s1, 0, 1)
      KSTEP(t + 1, s1, s0, 1, 0)
    }
#undef KSTEP

    // ---- per-pass epilogue: tanh + dot(v-slice) + 16-lane reduce ----
    {
      const float vv0 = v[slice * 64 +  0 + llo];
      const float vv1 = v[slice * 64 + 16 + llo];
      const float vv2 = v[slice * 64 + 32 + llo];
      const float vv3 = v[slice * 64 + 48 + llo];
#pragma unroll
      for (int mf = 0; mf < 4; ++mf) {
        float pr[4] = {0.f, 0.f, 0.f, 0.f};
#pragma unroll
        for (int r = 0; r < 4; ++r) {
          pr[r] += fast_tanh(acc[mf][0][r]) * vv0;
          pr[r] += fast_tanh(acc[mf][1][r]) * vv1;
          pr[r] += fast_tanh(acc[mf][2][r]) * vv2;
          pr[r] += fast_tanh(acc[mf][3][r]) * vv3;
        }
#pragma unroll
        for (int r = 0; r < 4; ++r) {
          float pp = pr[r];
          pp += __shfl_xor(pp, 1, 64);
          pp += __shfl_xor(pp, 2, 64);
          pp += __shfl_xor(pp, 4, 64);
          pp += __shfl_xor(pp, 8, 64);
          if (llo == 0) sp[mf * 16 + lhi * 4 + r][slice] = pp;
        }
      }
    }
  }
  __syncthreads();

  // ---- softmax over the 64 rows (wave 0) ----
  if (tid < BM) {
    float s = 0.f;
#pragma unroll
    for (int sl = 0; sl < 8; ++sl) s += sp[tid][sl];
    float mx = s;
#pragma unroll
    for (int mask = 1; mask < 64; mask <<= 1)
      mx = fmaxf(mx, __shfl_xor(mx, mask, 64));
    const float e = __builtin_amdgcn_exp2f((s - mx) * 1.442695040888963f);
    float sum = e;
#pragma unroll
    for (int mask = 1; mask < 64; mask <<= 1)
      sum += __shfl_xor(sum, mask, 64);
    attn[tid] = e * __builtin_amdgcn_rcpf(sum);
  }
  __syncthreads();

  // ---- out = sum_s attn[s]*x[m0+s][:], 256 threads x float4, MLP=4 ----
  const float* xg = x + (size_t)m0 * D_ + tid * 4;
  f32x4 o0 = {0.f,0.f,0.f,0.f}, o1 = o0, o2 = o0, o3 = o0;
#pragma unroll 4
  for (int s = 0; s < T2_; s += 4) {
    const float w0 = attn[s + 0];
    const float w1 = attn[s + 1];
    const float w2 = attn[s + 2];
    const float w3 = attn[s + 3];
    const float4 a0 = *(const float4*)(xg + (size_t)(s + 0) * D_);
    const float4 a1 = *(const float4*)(xg + (size_t)(s + 1) * D_);
    const float4 a2 = *(const float4*)(xg + (size_t)(s + 2) * D_);
    const float4 a3 = *(const float4*)(xg + (size_t)(s + 3) * D_);
    o0[0] += w0 * a0.x; o0[1] += w0 * a0.y; o0[2] += w0 * a0.z; o0[3] += w0 * a0.w;
    o1[0] += w1 * a1.x; o1[1] += w1 * a1.y; o1[2] += w1 * a1.z; o1[3] += w1 * a1.w;
    o2[0] += w2 * a2.x; o2[1] += w2 * a2.y; o2[2] += w2 * a2.z; o2[3] += w2 * a2.w;
    o3[0] += w3 * a3.x; o3[1] += w3 * a3.y; o3[2] += w3 * a3.z; o3[3] += w3 * a3.w;
  }
  float4 res = {(o0[0] + o1[0]) + (o2[0] + o3[0]),
                (o0[1] + o1[1]) + (o2[1] + o3[1]),
                (o0[2] + o1[2]) + (o2[2] + o3[2]),
                (o0[3] + o1[3]) + (o2[3] + o3[3])};
  *(float4*)(out + (size_t)bt * D_ + tid * 4) = res;
}

extern "C" void kernel_launch(void* const* d_in, const int* in_sizes, int n_in,
                              void* d_out, int out_size, void* d_ws, size_t ws_size,
                              hipStream_t stream) {
  const float* x = (const float*)d_in[0];   // (16,64,64,1024) fp32
  const float* W = (const float*)d_in[1];   // (1024,512) fp32
  const float* v = (const float*)d_in[2];   // (512,) fp32
  float* out = (float*)d_out;               // (16,64,1024) fp32
  unsigned short* Wt = (unsigned short*)d_ws;  // 1 MB fragment-ordered bf16

  make_bfrag<<<dim3(NT, PROJ_ / 32), 256, 0, stream>>>(W, Wt);
  fused_kernel<<<B_ * T1_, 256, 0, stream>>>(x, Wt, v, out);
}